// Round 3
// baseline (439.326 us; speedup 1.0000x reference)
//
#include <hip/hip_runtime.h>
#include <hip/hip_bf16.h>

#define NUM_USERS 100000
#define NUM_ITEMS 50000
#define EMBED_DIM 64
#define N_NODES   150000                 // NUM_USERS + NUM_ITEMS
#define ROW_SHIFT 9                      // 512 rows per bucket
#define ROWS_PER_BUCKET 512
#define B_BUCKETS ((N_NODES + ROWS_PER_BUCKET - 1) / ROWS_PER_BUCKET)   // 293
#define NBP 512                          // padded bucket-array size
#define BIN_CHUNK 2048                   // edges per bin block (4/thread @512)
#define COL_MASK 0x3FFFF                 // 18 bits for col (N_NODES < 262144)

typedef unsigned short ushort_t;
typedef unsigned int uint_t;
typedef __attribute__((ext_vector_type(4))) int i4;

__device__ __forceinline__ float bf16_to_f32(ushort_t u) {
    return __uint_as_float(((unsigned)u) << 16);
}
__device__ __forceinline__ ushort_t f32_to_bf16(float f) {
    return __builtin_bit_cast(ushort_t, __float2bfloat16(f));   // RNE
}

// ---------------------------------------------------------------------------
// k_bin2: heterogeneous grid. First g_conv blocks: fp32->bf16 ego convert.
// Remaining blocks: LDS-binned staging into FIXED-CAPACITY bucket regions
// (cap entries per bucket; cursor[b] counts fill). No histogram, no global
// scan needed — bucket b's region starts at b*cap.
// Staging entry: int2 {col | lrow<<18, val}.
// ---------------------------------------------------------------------------
__global__ void __launch_bounds__(512) k_bin2(const float* __restrict__ ue,
                                              const float* __restrict__ ie,
                                              ushort_t* __restrict__ xb,
                                              const int* __restrict__ rows,
                                              const int* __restrict__ cols,
                                              const float* __restrict__ vals,
                                              int* __restrict__ cursor,
                                              int2* __restrict__ staging,
                                              int nnz, int cap, int g_conv) {
    int t = threadIdx.x;
    if ((int)blockIdx.x < g_conv) {
        // ---- convert: fp32 ego table -> bf16 (float4 granularity) ----
        int i = blockIdx.x * 512 + t;
        const int n4 = (N_NODES * EMBED_DIM) / 4;
        if (i >= n4) return;
        const int usplit = (NUM_USERS * EMBED_DIM) / 4;
        float4 f = (i < usplit) ? ((const float4*)ue)[i] : ((const float4*)ie)[i - usplit];
        ushort4 o;
        o.x = f32_to_bf16(f.x);
        o.y = f32_to_bf16(f.y);
        o.z = f32_to_bf16(f.z);
        o.w = f32_to_bf16(f.w);
        ((ushort4*)xb)[i] = o;
        return;
    }

    // ---- binning ----
    __shared__ int  ccnt[NBP];
    __shared__ int  cpos[NBP];
    __shared__ int  gdst[NBP];
    __shared__ int2 entries[BIN_CHUNK];            // 16 KB
    __shared__ ushort_t ebuck[BIN_CHUNK];          // 4 KB

    int base = (blockIdx.x - g_conv) * BIN_CHUNK;
    ccnt[t] = 0;
    __syncthreads();

    int myrow[BIN_CHUNK / 512];
#pragma unroll
    for (int k = 0; k < BIN_CHUNK / 512; k++) {
        int idx = base + k * 512 + t;
        int r = (idx < nnz) ? rows[idx] : -1;
        myrow[k] = r;
        if (r >= 0) atomicAdd(&ccnt[r >> ROW_SHIFT], 1);
    }
    __syncthreads();

    int c = ccnt[t];
    cpos[t] = c;
    __syncthreads();
    for (int d = 1; d < NBP; d <<= 1) {
        int y = (t >= d) ? cpos[t - d] : 0;
        __syncthreads();
        cpos[t] += y;
        __syncthreads();
    }
    int total = cpos[NBP - 1];
    int excl = cpos[t] - c;
    __syncthreads();
    cpos[t] = excl;
    __syncthreads();

#pragma unroll
    for (int k = 0; k < BIN_CHUNK / 512; k++) {
        int r = myrow[k];
        if (r >= 0) {
            int idx = base + k * 512 + t;
            int b = r >> ROW_SHIFT;
            int lrow = r & (ROWS_PER_BUCKET - 1);
            int slot = atomicAdd(&cpos[b], 1);
            entries[slot] = make_int2(cols[idx] | (lrow << 18), __float_as_int(vals[idx]));
            ebuck[slot] = (ushort_t)b;
        }
    }
    __syncthreads();

    // reserve space in each touched bucket's fixed region
    if (t < B_BUCKETS && ccnt[t] > 0) {
        int g = atomicAdd(&cursor[t], ccnt[t]);
        gdst[t] = t * cap + g - (cpos[t] - ccnt[t]);   // minus local run base
    }
    __syncthreads();

    for (int i = t; i < total; i += 512) {
        int eb = ebuck[i];
        int pos = gdst[eb] + i;
        if (pos < (eb + 1) * cap)                     // capacity guard (never hits)
            staging[pos] = entries[i];
    }
}

// ---------------------------------------------------------------------------
// k_scatter2b: one block owns one bucket (512 rows, fixed region).
// Count -> scan -> scatter; writes per-row ranges {beg,end} into padded cv.
// ---------------------------------------------------------------------------
__global__ void __launch_bounds__(512) k_scatter2b(const int2* __restrict__ staging,
                                                   const int* __restrict__ cursor,
                                                   int2* __restrict__ ranges,
                                                   int2* __restrict__ cv, int cap) {
    __shared__ int rc[ROWS_PER_BUCKET];
    int b = blockIdx.x;
    int t = threadIdx.x;
    int rbase = b * cap;
    int cnt_b = cursor[b];
    if (cnt_b > cap) cnt_b = cap;
    int row0 = b << ROW_SHIFT;

    rc[t] = 0;
    __syncthreads();
    for (int i = t; i < cnt_b; i += 512)
        atomicAdd(&rc[staging[rbase + i].x >> 18], 1);
    __syncthreads();

    int c = rc[t];
    for (int d = 1; d < ROWS_PER_BUCKET; d <<= 1) {
        int y = (t >= d) ? rc[t - d] : 0;
        __syncthreads();
        rc[t] += y;
        __syncthreads();
    }
    int excl = rc[t] - c;
    int row = row0 + t;
    if (row < N_NODES) ranges[row] = make_int2(rbase + excl, rbase + excl + c);
    __syncthreads();
    rc[t] = excl;                        // becomes per-row cursor
    __syncthreads();

    for (int i = t; i < cnt_b; i += 512) {
        int2 e = staging[rbase + i];
        int pos = rbase + atomicAdd(&rc[e.x >> 18], 1);
        cv[pos] = make_int2(e.x & COL_MASK, e.y);
    }
}

// ---------------------------------------------------------------------------
// R15 scalar-stream SpMM row body.
// Edge stream read with s_load_dwordx4 (wave-uniform -> SMEM pipe, cols/vals
// land in SGPRs: no VGPR loads, no readfirstlane, no selects). Each edge's
// x-row gathered by the FULL wave: lane owns dim `lane` (u16), address =
// SGPR base (xb + col*128, SALU) + constant VGPR offset lane*2 -> zero VALU
// address math. Per-edge VALU = v_lshlrev (bf16->f32) + v_fmac (SGPR val).
// Groups of 8 edges, ping-pong prefetch (R12-proven depth). Tail = one
// masked 8-edge burst (uniform s_cselect masks; cols clamped before gather;
// s_load overreads stay inside the bucket's >=2000-entry padded slack).
// Rule-18 fence: s_waitcnt lgkmcnt(0) with "+s" pass-through + sched_barrier.
// ---------------------------------------------------------------------------
#define SL(A, B, C, D, P)                                                     \
    asm volatile("s_load_dwordx4 %0, %4, 0x0\n\t"                             \
                 "s_load_dwordx4 %1, %4, 0x10\n\t"                            \
                 "s_load_dwordx4 %2, %4, 0x20\n\t"                            \
                 "s_load_dwordx4 %3, %4, 0x30"                                \
                 : "=&s"(A), "=&s"(B), "=&s"(C), "=&s"(D)                     \
                 : "s"(P));

#define SF(A, B, C, D)                                                        \
    asm volatile("s_waitcnt lgkmcnt(0)"                                       \
                 : "+s"(A), "+s"(B), "+s"(C), "+s"(D) :: "memory");           \
    __builtin_amdgcn_sched_barrier(0);

#define GG(R, A, B, C, D)                                                     \
    R[0] = xr[((size_t)(uint_t)A.x << 6) + lane];                             \
    R[1] = xr[((size_t)(uint_t)A.z << 6) + lane];                             \
    R[2] = xr[((size_t)(uint_t)B.x << 6) + lane];                             \
    R[3] = xr[((size_t)(uint_t)B.z << 6) + lane];                             \
    R[4] = xr[((size_t)(uint_t)C.x << 6) + lane];                             \
    R[5] = xr[((size_t)(uint_t)C.z << 6) + lane];                             \
    R[6] = xr[((size_t)(uint_t)D.x << 6) + lane];                             \
    R[7] = xr[((size_t)(uint_t)D.z << 6) + lane];

#define CS(R, A, B, C, D)                                                     \
    acc += __int_as_float(A.y) * __uint_as_float((uint_t)R[0] << 16);         \
    acc += __int_as_float(A.w) * __uint_as_float((uint_t)R[1] << 16);         \
    acc += __int_as_float(B.y) * __uint_as_float((uint_t)R[2] << 16);         \
    acc += __int_as_float(B.w) * __uint_as_float((uint_t)R[3] << 16);         \
    acc += __int_as_float(C.y) * __uint_as_float((uint_t)R[4] << 16);         \
    acc += __int_as_float(C.w) * __uint_as_float((uint_t)R[5] << 16);         \
    acc += __int_as_float(D.y) * __uint_as_float((uint_t)R[6] << 16);         \
    acc += __int_as_float(D.w) * __uint_as_float((uint_t)R[7] << 16);

__device__ __forceinline__ float spmm_row_scalar(int beg, int end, int lane,
                                                 const int2* __restrict__ cv,
                                                 const ushort_t* __restrict__ xb) {
    const ushort_t* __restrict__ xr = xb;
    float acc = 0.f;
    int e = beg;
    int ne = end - beg;
    int ng = ne >> 3;                    // full groups of 8 edges

    i4 A0, B0, C0, D0, A1, B1, C1, D1;
    uint_t r0[8], r1[8];

    if (ng > 0) {
        SL(A0, B0, C0, D0, cv + e)
        SF(A0, B0, C0, D0)
        GG(r0, A0, B0, C0, D0)
        e += 8;
        int g = 1;
#pragma unroll 1
        for (; g + 1 < ng; g += 2) {
            SL(A1, B1, C1, D1, cv + e)
            SF(A1, B1, C1, D1)
            GG(r1, A1, B1, C1, D1)
            e += 8;
            CS(r0, A0, B0, C0, D0)
            SL(A0, B0, C0, D0, cv + e)
            SF(A0, B0, C0, D0)
            GG(r0, A0, B0, C0, D0)
            e += 8;
            CS(r1, A1, B1, C1, D1)
        }
        if (g < ng) {
            SL(A1, B1, C1, D1, cv + e)
            SF(A1, B1, C1, D1)
            GG(r1, A1, B1, C1, D1)
            e += 8;
            CS(r0, A0, B0, C0, D0)
            CS(r1, A1, B1, C1, D1)
        } else {
            CS(r0, A0, B0, C0, D0)
        }
    }

    // ---- masked 8-edge tail (rem in 1..7). s_load overread stays in the
    // bucket's padded slack; garbage cols clamped to 0 before the gather. ----
    int rem = end - e;                   // wave-uniform
    if (rem > 0) {
        SL(A0, B0, C0, D0, cv + e)
        SF(A0, B0, C0, D0)
#define TE(CC, VV, J)                                                         \
        { int cj = (J) < rem ? (int)(CC) : 0;                                 \
          float vj = (J) < rem ? __int_as_float(VV) : 0.0f;                   \
          uint_t rr = xr[((size_t)(uint_t)cj << 6) + lane];                   \
          acc += vj * __uint_as_float(rr << 16); }
        TE(A0.x, A0.y, 0) TE(A0.z, A0.w, 1)
        TE(B0.x, B0.y, 2) TE(B0.z, B0.w, 3)
        TE(C0.x, C0.y, 4) TE(C0.z, C0.w, 5)
        TE(D0.x, D0.y, 6) TE(D0.z, D0.w, 7)
#undef TE
    }
    return acc;
}

__global__ void k_spmm(const int2* __restrict__ ranges, const int2* __restrict__ cv,
                       const ushort_t* __restrict__ xb, ushort_t* __restrict__ out) {
    int row = (blockIdx.x * blockDim.x + threadIdx.x) >> 6;
    int lane = threadIdx.x & 63;
    if (row >= N_NODES) return;
    row = __builtin_amdgcn_readfirstlane(row);
    int2 rng = ranges[row];
    int beg = __builtin_amdgcn_readfirstlane(rng.x);
    int end = __builtin_amdgcn_readfirstlane(rng.y);
    float a = spmm_row_scalar(beg, end, lane, cv, xb);
    out[(size_t)row * 64 + lane] = f32_to_bf16(a);   // 64 lanes x 2B = 128B
}

// ---------------------------------------------------------------------------
// k_last: one wave per batch element. Computes layer-3 rows for BOTH the
// user node and item node (two spmm_rows), gathers ego(fp32)+xbA+xbB, and
// emits the dot. Lane owns dim `lane`; full 64-lane reduce; scale 1/16
// (mean = acc/4 for each side).
// ---------------------------------------------------------------------------
__global__ void k_last(const int2* __restrict__ ranges, const int2* __restrict__ cv,
                       const int* __restrict__ users, const int* __restrict__ items,
                       const float* __restrict__ ue, const float* __restrict__ ie,
                       const ushort_t* __restrict__ xbA, const ushort_t* __restrict__ xbB,
                       float* __restrict__ out, int batch) {
    int w = (blockIdx.x * blockDim.x + threadIdx.x) >> 6;
    int lane = threadIdx.x & 63;
    if (w >= batch) return;

    int uu = __builtin_amdgcn_readfirstlane(users[w]);
    int ii = __builtin_amdgcn_readfirstlane(items[w]);
    int row_u = uu;
    int row_i = NUM_USERS + ii;

    // layer-3 contributions (source = xbB)
    int2 ru = ranges[row_u];
    float a_u = spmm_row_scalar(__builtin_amdgcn_readfirstlane(ru.x),
                                __builtin_amdgcn_readfirstlane(ru.y), lane, cv, xbB);
    int2 ri = ranges[row_i];
    float a_i = spmm_row_scalar(__builtin_amdgcn_readfirstlane(ri.x),
                                __builtin_amdgcn_readfirstlane(ri.y), lane, cv, xbB);

    float e_u = ue[(size_t)uu * EMBED_DIM + lane];
    float e_i = ie[(size_t)ii * EMBED_DIM + lane];
    float Au = bf16_to_f32(xbA[(size_t)row_u * 64 + lane]);
    float Bu = bf16_to_f32(xbB[(size_t)row_u * 64 + lane]);
    float Ai = bf16_to_f32(xbA[(size_t)row_i * 64 + lane]);
    float Bi = bf16_to_f32(xbB[(size_t)row_i * 64 + lane]);

    float ux = e_u + Au + Bu + a_u;
    float ix = e_i + Ai + Bi + a_i;

    float p = ux * ix;
#pragma unroll
    for (int d = 32; d > 0; d >>= 1) p += __shfl_down(p, d, 64);
    if (lane == 0) out[w] = p * (1.0f / 16.0f);   // 1/16 mean^2 scale
}

// ---------------------------------------------------------------------------

extern "C" void kernel_launch(void* const* d_in, const int* in_sizes, int n_in,
                              void* d_out, int out_size, void* d_ws, size_t ws_size,
                              hipStream_t stream) {
    const int*   users    = (const int*)  d_in[0];
    const int*   items    = (const int*)  d_in[1];
    const int*   adj_rows = (const int*)  d_in[2];
    const int*   adj_cols = (const int*)  d_in[3];
    const float* adj_vals = (const float*)d_in[4];
    const float* user_emb = (const float*)d_in[5];
    const float* item_emb = (const float*)d_in[6];
    float* out = (float*)d_out;

    const int batch = in_sizes[0];
    const int nnz   = in_sizes[2];

    // fixed bucket capacity: mean * 9/8, rounded up to 64 (16-sigma margin)
    int cap = ((nnz / B_BUCKETS) * 9 + 7) / 8;
    cap = (cap + 63) & ~63;
    const size_t padded = (size_t)B_BUCKETS * cap;   // ~5.4M entries

    char* p = (char*)d_ws;
    auto alloc = [&](size_t bytes) -> char* {
        char* r = p;
        p += (bytes + 255) & ~(size_t)255;
        return r;
    };
    const size_t xb_bytes = (size_t)N_NODES * EMBED_DIM * 2;       // 19.2 MB
    int2*     ranges = (int2*) alloc((size_t)N_NODES * 8);
    int*      cursor = (int*)  alloc(NBP * 4);
    int2*     cv     = (int2*) alloc(padded * 8);                  // padded CSR
    // region overlays: staging (build) vs xbA+xbB (layer buffers)
    size_t    region_bytes = padded * 8;
    if (region_bytes < 2 * xb_bytes) region_bytes = 2 * xb_bytes;
    char*     region  = alloc(region_bytes);
    int2*     staging = (int2*)region;
    ushort_t* xbA     = (ushort_t*)region;
    ushort_t* xbB     = (ushort_t*)(region + xb_bytes);
    ushort_t* xb_ego  = (ushort_t*)alloc(xb_bytes);

    const int g_conv  = ((N_NODES * EMBED_DIM / 4) + 511) / 512;   // 4688
    const int g_bin   = (nnz + BIN_CHUNK - 1) / BIN_CHUNK;         // 2344
    const int g_nodes = (N_NODES + 3) / 4;                         // 4 waves/block
    const int g_batch = (batch + 3) / 4;

    // ---- build: convert + fixed-capacity binning (one grid), then scatter ----
    hipMemsetAsync(cursor, 0, NBP * 4, stream);
    k_bin2<<<g_conv + g_bin, 512, 0, stream>>>(user_emb, item_emb, xb_ego,
                                               adj_rows, adj_cols, adj_vals,
                                               cursor, staging, nnz, cap, g_conv);
    k_scatter2b<<<B_BUCKETS, 512, 0, stream>>>(staging, cursor, ranges, cv, cap);

    // ---- layer 1: xbA = A * ego ----
    k_spmm<<<g_nodes, 256, 0, stream>>>(ranges, cv, xb_ego, xbA);

    // ---- layer 2: xbB = A * xbA ----
    k_spmm<<<g_nodes, 256, 0, stream>>>(ranges, cv, xbA, xbB);

    // ---- layer 3 (batch rows only) + gather + dot, fused ----
    k_last<<<g_batch, 256, 0, stream>>>(ranges, cv, users, items,
                                        user_emb, item_emb, xbA, xbB, out, batch);
}

// Round 4
// 430.120 us; speedup vs baseline: 1.0214x; 1.0214x over previous
//
#include <hip/hip_runtime.h>
#include <hip/hip_bf16.h>

#define NUM_USERS 100000
#define NUM_ITEMS 50000
#define EMBED_DIM 64
#define N_NODES   150000                 // NUM_USERS + NUM_ITEMS
#define ROW_SHIFT 9                      // 512 rows per bucket
#define ROWS_PER_BUCKET 512
#define B_BUCKETS ((N_NODES + ROWS_PER_BUCKET - 1) / ROWS_PER_BUCKET)   // 293
#define NBP 512                          // padded bucket-array size
#define BIN_CHUNK 2048                   // edges per bin block (4/thread @512)
#define COL_MASK 0x3FFFF                 // 18 bits for col (N_NODES < 262144)

typedef unsigned short ushort_t;
typedef unsigned int uint_t;

__device__ __forceinline__ float bf16_to_f32(ushort_t u) {
    return __uint_as_float(((unsigned)u) << 16);
}
__device__ __forceinline__ ushort_t f32_to_bf16(float f) {
    return __builtin_bit_cast(ushort_t, __float2bfloat16(f));   // RNE
}

// ---------------------------------------------------------------------------
// k_bin2: heterogeneous grid. First g_conv blocks: fp32->bf16 ego convert.
// Remaining blocks: LDS-binned staging into FIXED-CAPACITY bucket regions
// (cap entries per bucket; cursor[b] counts fill). No histogram, no global
// scan needed — bucket b's region starts at b*cap.
// Staging entry: int2 {col | lrow<<18, val}.
// ---------------------------------------------------------------------------
__global__ void __launch_bounds__(512) k_bin2(const float* __restrict__ ue,
                                              const float* __restrict__ ie,
                                              ushort_t* __restrict__ xb,
                                              const int* __restrict__ rows,
                                              const int* __restrict__ cols,
                                              const float* __restrict__ vals,
                                              int* __restrict__ cursor,
                                              int2* __restrict__ staging,
                                              int nnz, int cap, int g_conv) {
    int t = threadIdx.x;
    if ((int)blockIdx.x < g_conv) {
        // ---- convert: fp32 ego table -> bf16 (float4 granularity) ----
        int i = blockIdx.x * 512 + t;
        const int n4 = (N_NODES * EMBED_DIM) / 4;
        if (i >= n4) return;
        const int usplit = (NUM_USERS * EMBED_DIM) / 4;
        float4 f = (i < usplit) ? ((const float4*)ue)[i] : ((const float4*)ie)[i - usplit];
        ushort4 o;
        o.x = f32_to_bf16(f.x);
        o.y = f32_to_bf16(f.y);
        o.z = f32_to_bf16(f.z);
        o.w = f32_to_bf16(f.w);
        ((ushort4*)xb)[i] = o;
        return;
    }

    // ---- binning ----
    __shared__ int  ccnt[NBP];
    __shared__ int  cpos[NBP];
    __shared__ int  gdst[NBP];
    __shared__ int2 entries[BIN_CHUNK];            // 16 KB
    __shared__ ushort_t ebuck[BIN_CHUNK];          // 4 KB

    int base = (blockIdx.x - g_conv) * BIN_CHUNK;
    ccnt[t] = 0;
    __syncthreads();

    int myrow[BIN_CHUNK / 512];
#pragma unroll
    for (int k = 0; k < BIN_CHUNK / 512; k++) {
        int idx = base + k * 512 + t;
        int r = (idx < nnz) ? rows[idx] : -1;
        myrow[k] = r;
        if (r >= 0) atomicAdd(&ccnt[r >> ROW_SHIFT], 1);
    }
    __syncthreads();

    int c = ccnt[t];
    cpos[t] = c;
    __syncthreads();
    for (int d = 1; d < NBP; d <<= 1) {
        int y = (t >= d) ? cpos[t - d] : 0;
        __syncthreads();
        cpos[t] += y;
        __syncthreads();
    }
    int total = cpos[NBP - 1];
    int excl = cpos[t] - c;
    __syncthreads();
    cpos[t] = excl;
    __syncthreads();

#pragma unroll
    for (int k = 0; k < BIN_CHUNK / 512; k++) {
        int r = myrow[k];
        if (r >= 0) {
            int idx = base + k * 512 + t;
            int b = r >> ROW_SHIFT;
            int lrow = r & (ROWS_PER_BUCKET - 1);
            int slot = atomicAdd(&cpos[b], 1);
            entries[slot] = make_int2(cols[idx] | (lrow << 18), __float_as_int(vals[idx]));
            ebuck[slot] = (ushort_t)b;
        }
    }
    __syncthreads();

    // reserve space in each touched bucket's fixed region
    if (t < B_BUCKETS && ccnt[t] > 0) {
        int g = atomicAdd(&cursor[t], ccnt[t]);
        gdst[t] = t * cap + g - (cpos[t] - ccnt[t]);   // minus local run base
    }
    __syncthreads();

    for (int i = t; i < total; i += 512) {
        int eb = ebuck[i];
        int pos = gdst[eb] + i;
        if (pos < (eb + 1) * cap)                     // capacity guard (never hits)
            staging[pos] = entries[i];
    }
}

// ---------------------------------------------------------------------------
// k_scatter2b: one block owns one bucket (512 rows, fixed region).
// Count -> scan -> scatter; writes per-row ranges {beg,end} into padded cv.
// ---------------------------------------------------------------------------
__global__ void __launch_bounds__(512) k_scatter2b(const int2* __restrict__ staging,
                                                   const int* __restrict__ cursor,
                                                   int2* __restrict__ ranges,
                                                   int2* __restrict__ cv, int cap) {
    __shared__ int rc[ROWS_PER_BUCKET];
    int b = blockIdx.x;
    int t = threadIdx.x;
    int rbase = b * cap;
    int cnt_b = cursor[b];
    if (cnt_b > cap) cnt_b = cap;
    int row0 = b << ROW_SHIFT;

    rc[t] = 0;
    __syncthreads();
    for (int i = t; i < cnt_b; i += 512)
        atomicAdd(&rc[staging[rbase + i].x >> 18], 1);
    __syncthreads();

    int c = rc[t];
    for (int d = 1; d < ROWS_PER_BUCKET; d <<= 1) {
        int y = (t >= d) ? rc[t - d] : 0;
        __syncthreads();
        rc[t] += y;
        __syncthreads();
    }
    int excl = rc[t] - c;
    int row = row0 + t;
    if (row < N_NODES) ranges[row] = make_int2(rbase + excl, rbase + excl + c);
    __syncthreads();
    rc[t] = excl;                        // becomes per-row cursor
    __syncthreads();

    for (int i = t; i < cnt_b; i += 512) {
        int2 e = staging[rbase + i];
        int pos = rbase + atomicAdd(&rc[e.x >> 18], 1);
        cv[pos] = make_int2(e.x & COL_MASK, e.y);
    }
}

// ---------------------------------------------------------------------------
// R16 readlane-broadcast SpMM row body.
// Edge stream: lane l loads edge beg+l with ONE coalesced global_load_dwordx2
// (64 edges / 512B / one vmcnt entry) -> one long-latency wait per 64 edges
// instead of one lgkmcnt(0) SMEM drain per 8 (R15's exposed ~900cy x 4.7
// groups per row was the wall). Invalid lanes clamp col->0 / val->0 (row 0
// stays L1-hot, contributes 0) — no tail machinery. Each edge is broadcast
// via v_readlane (uniform dynamic index): col feeds SGPR-based gather
// address, val feeds v_fmac as the scalar operand. Gathers issue in a
// 32-wide window (4 groups of 8, uniform guards, static reg indexing), then
// drain in-order: group 0's consume runs with 24 gathers still outstanding.
// Overreads stay inside the bucket's >=2000-entry padded slack (16 sigma).
// ---------------------------------------------------------------------------
#define ISSUE8(R, J0)                                                         \
    _Pragma("unroll")                                                         \
    for (int j = 0; j < 8; j++) {                                             \
        int sc = __builtin_amdgcn_readlane(vc, (J0) + j);                     \
        R[j] = xb[((size_t)(uint_t)sc << 6) + lane];                          \
    }

#define CONS8(R, J0)                                                          \
    _Pragma("unroll")                                                         \
    for (int j = 0; j < 8; j++) {                                             \
        float sv = __uint_as_float((uint_t)__builtin_amdgcn_readlane(vv, (J0) + j)); \
        acc += sv * __uint_as_float((uint_t)R[j] << 16);                      \
    }

__device__ __forceinline__ float spmm_row_rl(int beg, int end, int lane,
                                             const int2* __restrict__ cv,
                                             const ushort_t* __restrict__ xb) {
    float acc = 0.f;
#pragma unroll 1
    for (int b = beg; b < end; b += 64) {
        int2 ed = cv[b + lane];              // coalesced 512B, 1 vmcnt entry
        bool lv = (b + lane) < end;
        int vc = lv ? ed.x : 0;              // per-lane clamp (2 cndmask)
        int vv = lv ? ed.y : 0;
        int rem = end - b;                   // wave-uniform
        if (rem > 64) rem = 64;

        ushort_t q0[8], q1[8], q2[8], q3[8];
        // ---- half 0: edges 0..31 ----
        ISSUE8(q0, 0)
        if (rem > 8)  { ISSUE8(q1, 8)  }
        if (rem > 16) { ISSUE8(q2, 16) }
        if (rem > 24) { ISSUE8(q3, 24) }
        CONS8(q0, 0)
        if (rem > 8)  { CONS8(q1, 8)  }
        if (rem > 16) { CONS8(q2, 16) }
        if (rem > 24) { CONS8(q3, 24) }
        // ---- half 1: edges 32..63 ----
        if (rem > 32) {
            ISSUE8(q0, 32)
            if (rem > 40) { ISSUE8(q1, 40) }
            if (rem > 48) { ISSUE8(q2, 48) }
            if (rem > 56) { ISSUE8(q3, 56) }
            CONS8(q0, 32)
            if (rem > 40) { CONS8(q1, 40) }
            if (rem > 48) { CONS8(q2, 48) }
            if (rem > 56) { CONS8(q3, 56) }
        }
    }
    return acc;
}

__global__ void k_spmm(const int2* __restrict__ ranges, const int2* __restrict__ cv,
                       const ushort_t* __restrict__ xb, ushort_t* __restrict__ out) {
    int row = (blockIdx.x * blockDim.x + threadIdx.x) >> 6;
    int lane = threadIdx.x & 63;
    if (row >= N_NODES) return;
    row = __builtin_amdgcn_readfirstlane(row);
    int2 rng = ranges[row];
    int beg = __builtin_amdgcn_readfirstlane(rng.x);
    int end = __builtin_amdgcn_readfirstlane(rng.y);
    float a = spmm_row_rl(beg, end, lane, cv, xb);
    out[(size_t)row * 64 + lane] = f32_to_bf16(a);   // 64 lanes x 2B = 128B
}

// ---------------------------------------------------------------------------
// k_last: one wave per batch element. Computes layer-3 rows for BOTH the
// user node and item node (two spmm_rows), gathers ego(fp32)+xbA+xbB, and
// emits the dot. Lane owns dim `lane`; full 64-lane reduce; scale 1/16
// (mean = acc/4 for each side).
// ---------------------------------------------------------------------------
__global__ void k_last(const int2* __restrict__ ranges, const int2* __restrict__ cv,
                       const int* __restrict__ users, const int* __restrict__ items,
                       const float* __restrict__ ue, const float* __restrict__ ie,
                       const ushort_t* __restrict__ xbA, const ushort_t* __restrict__ xbB,
                       float* __restrict__ out, int batch) {
    int w = (blockIdx.x * blockDim.x + threadIdx.x) >> 6;
    int lane = threadIdx.x & 63;
    if (w >= batch) return;

    int uu = __builtin_amdgcn_readfirstlane(users[w]);
    int ii = __builtin_amdgcn_readfirstlane(items[w]);
    int row_u = uu;
    int row_i = NUM_USERS + ii;

    // layer-3 contributions (source = xbB)
    int2 ru = ranges[row_u];
    float a_u = spmm_row_rl(__builtin_amdgcn_readfirstlane(ru.x),
                            __builtin_amdgcn_readfirstlane(ru.y), lane, cv, xbB);
    int2 ri = ranges[row_i];
    float a_i = spmm_row_rl(__builtin_amdgcn_readfirstlane(ri.x),
                            __builtin_amdgcn_readfirstlane(ri.y), lane, cv, xbB);

    float e_u = ue[(size_t)uu * EMBED_DIM + lane];
    float e_i = ie[(size_t)ii * EMBED_DIM + lane];
    float Au = bf16_to_f32(xbA[(size_t)row_u * 64 + lane]);
    float Bu = bf16_to_f32(xbB[(size_t)row_u * 64 + lane]);
    float Ai = bf16_to_f32(xbA[(size_t)row_i * 64 + lane]);
    float Bi = bf16_to_f32(xbB[(size_t)row_i * 64 + lane]);

    float ux = e_u + Au + Bu + a_u;
    float ix = e_i + Ai + Bi + a_i;

    float p = ux * ix;
#pragma unroll
    for (int d = 32; d > 0; d >>= 1) p += __shfl_down(p, d, 64);
    if (lane == 0) out[w] = p * (1.0f / 16.0f);   // 1/16 mean^2 scale
}

// ---------------------------------------------------------------------------

extern "C" void kernel_launch(void* const* d_in, const int* in_sizes, int n_in,
                              void* d_out, int out_size, void* d_ws, size_t ws_size,
                              hipStream_t stream) {
    const int*   users    = (const int*)  d_in[0];
    const int*   items    = (const int*)  d_in[1];
    const int*   adj_rows = (const int*)  d_in[2];
    const int*   adj_cols = (const int*)  d_in[3];
    const float* adj_vals = (const float*)d_in[4];
    const float* user_emb = (const float*)d_in[5];
    const float* item_emb = (const float*)d_in[6];
    float* out = (float*)d_out;

    const int batch = in_sizes[0];
    const int nnz   = in_sizes[2];

    // fixed bucket capacity: mean * 9/8, rounded up to 64 (16-sigma margin)
    int cap = ((nnz / B_BUCKETS) * 9 + 7) / 8;
    cap = (cap + 63) & ~63;
    const size_t padded = (size_t)B_BUCKETS * cap;   // ~5.4M entries

    char* p = (char*)d_ws;
    auto alloc = [&](size_t bytes) -> char* {
        char* r = p;
        p += (bytes + 255) & ~(size_t)255;
        return r;
    };
    const size_t xb_bytes = (size_t)N_NODES * EMBED_DIM * 2;       // 19.2 MB
    int2*     ranges = (int2*) alloc((size_t)N_NODES * 8);
    int*      cursor = (int*)  alloc(NBP * 4);
    int2*     cv     = (int2*) alloc(padded * 8);                  // padded CSR
    // region overlays: staging (build) vs xbA+xbB (layer buffers)
    size_t    region_bytes = padded * 8;
    if (region_bytes < 2 * xb_bytes) region_bytes = 2 * xb_bytes;
    char*     region  = alloc(region_bytes);
    int2*     staging = (int2*)region;
    ushort_t* xbA     = (ushort_t*)region;
    ushort_t* xbB     = (ushort_t*)(region + xb_bytes);
    ushort_t* xb_ego  = (ushort_t*)alloc(xb_bytes);

    const int g_conv  = ((N_NODES * EMBED_DIM / 4) + 511) / 512;   // 4688
    const int g_bin   = (nnz + BIN_CHUNK - 1) / BIN_CHUNK;         // 2344
    const int g_nodes = (N_NODES + 3) / 4;                         // 4 waves/block
    const int g_batch = (batch + 3) / 4;

    // ---- build: convert + fixed-capacity binning (one grid), then scatter ----
    hipMemsetAsync(cursor, 0, NBP * 4, stream);
    k_bin2<<<g_conv + g_bin, 512, 0, stream>>>(user_emb, item_emb, xb_ego,
                                               adj_rows, adj_cols, adj_vals,
                                               cursor, staging, nnz, cap, g_conv);
    k_scatter2b<<<B_BUCKETS, 512, 0, stream>>>(staging, cursor, ranges, cv, cap);

    // ---- layer 1: xbA = A * ego ----
    k_spmm<<<g_nodes, 256, 0, stream>>>(ranges, cv, xb_ego, xbA);

    // ---- layer 2: xbB = A * xbA ----
    k_spmm<<<g_nodes, 256, 0, stream>>>(ranges, cv, xbA, xbB);

    // ---- layer 3 (batch rows only) + gather + dot, fused ----
    k_last<<<g_batch, 256, 0, stream>>>(ranges, cv, users, items,
                                        user_emb, item_emb, xbA, xbB, out, batch);
}